// Round 5
// baseline (257.372 us; speedup 1.0000x reference)
//
#include <hip/hip_runtime.h>
#include <hip/hip_bf16.h>
#include <cstdint>
#include <cstddef>

typedef __bf16 bf16;
typedef __attribute__((ext_vector_type(8))) __bf16 bf16x8;
typedef __attribute__((ext_vector_type(4))) __bf16 bf16x4v;
typedef __attribute__((ext_vector_type(4))) float f32x4;

#define NB 2
#define NT 2048
#define NE 2048
#define NH 32
#define NHKV 8
#define ND 64
#define NBT (NB * NT)
#define NQKV 3072

__device__ __forceinline__ void gload_lds16(const void* g, void* l) {
  __builtin_amdgcn_global_load_lds(
      (const __attribute__((address_space(1))) unsigned int*)g,
      (__attribute__((address_space(3))) unsigned int*)l, 16, 0, 0);
}

// XOR swizzle for 128-byte LDS rows: spreads the 16-way bank conflict.
__device__ __forceinline__ int swz(int row, int byteoff) {
  return (row * 128 + byteoff) ^ ((row & 7) << 4);
}

// ---------------------------------------------------------------- pack kernels

__global__ void cvt_bf16_kernel(const float* __restrict__ in, bf16* __restrict__ out, int n4) {
  int i = blockIdx.x * blockDim.x + threadIdx.x;
  const int stride = gridDim.x * blockDim.x;
  for (; i < n4; i += stride) {
    const float4 v = ((const float4*)in)[i];
    bf16x4v o;
    o[0] = (bf16)v.x; o[1] = (bf16)v.y; o[2] = (bf16)v.z; o[3] = (bf16)v.w;
    ((bf16x4v*)out)[i] = o;
  }
}

// out[rowoff + c][k] = (bf16) in[k][c];  in: [2048][ncols] fp32, out LD = 2048
__global__ void transpose_cvt_kernel(const float* __restrict__ in, bf16* __restrict__ out,
                                     int ncols, int rowoff) {
  __shared__ float tile[32][33];
  const int c0 = blockIdx.x * 32;
  const int k0 = blockIdx.y * 32;
  const int tx = threadIdx.x, ty = threadIdx.y;
#pragma unroll
  for (int j = 0; j < 4; ++j)
    tile[ty + j * 8][tx] = in[(size_t)(k0 + ty + j * 8) * ncols + c0 + tx];
  __syncthreads();
#pragma unroll
  for (int j = 0; j < 4; ++j)
    out[(size_t)(rowoff + c0 + ty + j * 8) * 2048 + k0 + tx] = (bf16)tile[tx][ty + j * 8];
}

__global__ void rope_table_kernel(float* __restrict__ tab) {
  int i = blockIdx.x * 256 + threadIdx.x;
  if (i >= NT * 32) return;
  const int t = i >> 5, d = i & 31;
  const float inv = expf(-(float)d * 0.28782313662425574f);  // ln(10000)/32
  const float ang = (float)t * inv;
  tab[t * 64 + d] = cosf(ang);
  tab[t * 64 + 32 + d] = sinf(ang);
}

// vt[b][hk][d][t] = qkv[b*T+t][2560 + hk*64 + d]
__global__ void build_vt_kernel(const bf16* __restrict__ qkv, bf16* __restrict__ vt) {
  __shared__ bf16 tile[32][33];
  const int bhk = blockIdx.z;
  const int b = bhk >> 3, hk = bhk & 7;
  const int d0 = blockIdx.x * 32, t0 = blockIdx.y * 32;
  const int tx = threadIdx.x, ty = threadIdx.y;
#pragma unroll
  for (int j = 0; j < 4; ++j)
    tile[ty + j * 8][tx] = qkv[(size_t)(b * NT + t0 + ty + j * 8) * NQKV + 2560 + hk * 64 + d0 + tx];
  __syncthreads();
#pragma unroll
  for (int j = 0; j < 4; ++j)
    vt[((size_t)(b * NHKV + hk) * 64 + d0 + ty + j * 8) * NT + t0 + tx] = tile[tx][ty + j * 8];
}

// ---------------------------------------------------------------- GEMM (ring-3 pipelined)
// C[M][N] = A[M][K] * Bt[N][K]^T.  BM=256, BN=128, BK=64, 512 thr / 8 waves
// (4M x 2N), per-wave 64x64.  3-deep LDS ring of K-tiles: tile t+2's loads
// issue during tile t (prefetch distance = 2 tiles = 4 MFMA phases of cover).
// ONE vmcnt + ONE barrier per K-tile; steady-state vmcnt(6) keeps tile t+1's
// loads in flight across the barrier (T4).  Within a tile: both halves'
// ds_reads issue up front; lgkmcnt(8) lets half1's reads complete under
// half0's MFMAs.  T2 source-side swizzle, T5 setprio, XCD-bijective grid.
// Fragment/staging math identical to the round-4 kernel (correctness-proven).

template <typename CT, bool ROPE>
__global__ __launch_bounds__(512, 2)
void gemm8p_kernel(const bf16* __restrict__ A, const bf16* __restrict__ Bt,
                   CT* __restrict__ C, int M, int N, int K,
                   const float* __restrict__ tab) {
  __shared__ __align__(16) bf16 LA[3][2][8192];
  __shared__ __align__(16) bf16 LB[3][2][4096];
  const int tid = threadIdx.x, lane = tid & 63, w = tid >> 6;
  const int wm = w >> 1, wn = w & 1;
  const int gx = N >> 7;
  const int cpx = (int)gridDim.x >> 3;
  const int swzb = ((int)blockIdx.x & 7) * cpx + ((int)blockIdx.x >> 3);
  const int bx = swzb % gx, by = swzb / gx;
  const int m0 = by * 256, n0 = bx * 128;

  // staging source (per lane): row + swizzled k-offset
  const int srow = w * 16 + 2 * (lane >> 3) + ((lane >> 2) & 1);
  const int ke = 8 * ((lane & 3) ^ ((lane >> 3) & 3));
  const bf16* gA = A + (size_t)(m0 + srow) * K + ke;
  const bf16* gB = Bt + (size_t)(n0 + srow) * K + ke;
  const size_t rowK128 = (size_t)128 * K;
  const int NTK = K >> 6;

  // frag read offsets (elements):
  //   elem = (base32 + f*8 + (fr>>1))*64 + (fr&1)*32 + 8*(fq ^ ((fr>>1)&3))
  const int fr = lane & 15, fq = lane >> 4;
  const int fcol = (fr & 1) * 32 + 8 * (fq ^ ((fr >> 1) & 3));
  const int abase = (wm * 32 + (fr >> 1)) * 64 + fcol;
  const int bbase = (wn * 32 + (fr >> 1)) * 64 + fcol;

  f32x4 acc[4][4] = {};

#define STAGE_HALF(buf, ks, kg)                                                   \
  do {                                                                            \
    gload_lds16(gA + (kg) + (ks) * 32, &LA[buf][ks][tid * 8]);                    \
    gload_lds16(gA + (kg) + (ks) * 32 + rowK128, &LA[buf][ks][4096 + tid * 8]);   \
    gload_lds16(gB + (kg) + (ks) * 32, &LB[buf][ks][tid * 8]);                    \
  } while (0)

  STAGE_HALF(0, 0, 0);
  STAGE_HALF(0, 1, 0);
  STAGE_HALF(1, 0, 64);
  STAGE_HALF(1, 1, 64);

  int bc = 0;
  for (int t = 0; t < NTK; ++t) {
    if (t + 1 < NTK) asm volatile("s_waitcnt vmcnt(6)" ::: "memory");
    else             asm volatile("s_waitcnt vmcnt(0)" ::: "memory");
    __builtin_amdgcn_s_barrier();

    bf16x8 a0[4], b0[4], a1[4], b1[4];
#pragma unroll
    for (int f = 0; f < 4; ++f) {
      a0[f] = *(const bf16x8*)&LA[bc][0][abase + f * 512];
      b0[f] = *(const bf16x8*)&LB[bc][0][bbase + f * 512];
    }
    const int pb = (bc + 2 >= 3) ? bc - 1 : bc + 2;  // (bc+2)%3
    const bool pre = (t + 2 < NTK);
    if (pre) STAGE_HALF(pb, 0, (t + 2) * 64);
#pragma unroll
    for (int f = 0; f < 4; ++f) {
      a1[f] = *(const bf16x8*)&LA[bc][1][abase + f * 512];
      b1[f] = *(const bf16x8*)&LB[bc][1][bbase + f * 512];
    }
    asm volatile("s_waitcnt lgkmcnt(8)" ::: "memory");
    __builtin_amdgcn_sched_barrier(0);
    __builtin_amdgcn_s_setprio(1);
#pragma unroll
    for (int i = 0; i < 4; ++i)
#pragma unroll
      for (int j = 0; j < 4; ++j)
        acc[i][j] = __builtin_amdgcn_mfma_f32_16x16x32_bf16(a0[i], b0[j], acc[i][j], 0, 0, 0);
    __builtin_amdgcn_s_setprio(0);
    if (pre) STAGE_HALF(pb, 1, (t + 2) * 64);
    asm volatile("s_waitcnt lgkmcnt(0)" ::: "memory");
    __builtin_amdgcn_sched_barrier(0);
    __builtin_amdgcn_s_setprio(1);
#pragma unroll
    for (int i = 0; i < 4; ++i)
#pragma unroll
      for (int j = 0; j < 4; ++j)
        acc[i][j] = __builtin_amdgcn_mfma_f32_16x16x32_bf16(a1[i], b1[j], acc[i][j], 0, 0, 0);
    __builtin_amdgcn_s_setprio(0);
    bc = (bc + 1 == 3) ? 0 : bc + 1;
  }
#undef STAGE_HALF

  const bool do_rope = ROPE && (n0 + wn * 64) < 2560;
#pragma unroll
  for (int i = 0; i < 4; ++i) {
#pragma unroll
    for (int jj = 0; jj < 4; ++jj) {
      const int row = m0 + wm * 64 + i * 16 + fq * 4 + jj;
      float v0 = acc[i][0][jj], v1 = acc[i][1][jj], v2 = acc[i][2][jj], v3 = acc[i][3][jj];
      if (do_rope) {
        const int tt = row & (NT - 1);
        const float c0 = tab[tt * 64 + fr],      s0 = tab[tt * 64 + 32 + fr];
        const float c1 = tab[tt * 64 + 16 + fr], s1 = tab[tt * 64 + 48 + fr];
        const float a0 = v0, a2 = v2;
        v0 = a0 * c0 - a2 * s0;
        v2 = a2 * c0 + a0 * s0;
        const float a1 = v1, a3 = v3;
        v1 = a1 * c1 - a3 * s1;
        v3 = a3 * c1 + a1 * s1;
      }
      CT* cp = &C[(size_t)row * N + n0 + wn * 64 + fr];
      cp[0] = (CT)v0; cp[16] = (CT)v1; cp[32] = (CT)v2; cp[48] = (CT)v3;
    }
  }
}

// ---------------------------------------------------------------- attention
// Swapped-operand flash attention. One block = 128 q rows of one (b,h).
// 4 waves x 32 q rows (2 sets of 16). KVBLK = 64, causal.
// Grid is 1-D global big-first (uniform per-CU work; same-bh blocks land on
// the same XCD). K is stored row-PERMUTED in LDS (source-permuted
// global_load_lds, linear dest) so kf reads are bank-conflict-free.
// Softmax in log2 domain with defer-max (T13); setprio around MFMA (T5).

__global__ __launch_bounds__(256)
void attn_kernel(const bf16* __restrict__ qkv, const bf16* __restrict__ vt,
                 bf16* __restrict__ y) {
  const int bid = blockIdx.x;
  const int qtb = 15 - (bid >> 6);   // big blocks dispatched first
  const int bh = bid & 63;
  const int b = bh >> 5, h = bh & 31, hk = h >> 2;
  const int q0 = qtb * 128;

  __shared__ __align__(16) bf16 Kb0[4096], Kb1[4096], Vb0[4096], Vb1[4096];

  const int tid = threadIdx.x;
  const int lane = tid & 63, wid = tid >> 6;
  const int ql = lane & 15;
  const int sub = lane >> 4;

  // staging: dest linear row st_r / st_r+32, chunk tid&7; source column chunk
  // pre-swizzled by dest row (rule #21); K source ROW permuted so that LDS
  // row u holds kv 32(n>>1)+4(n&1)+8(t>>2)+(t&3), n=u>>4, t=u&15.
  const int st_r = tid >> 3;
  const int kperm = 4 * (st_r >> 4) + 8 * ((st_r >> 2) & 3) + (st_r & 3);
  const int csw = ((tid & 7) ^ (st_r & 7)) * 8;
  const bf16* kgbase = qkv + (size_t)(b * NT + kperm) * NQKV + 2048 + hk * 64 + csw;
  const bf16* vgbase = vt + ((size_t)(b * NHKV + hk) * 64 + st_r) * NT + csw;

  auto STAGE = [&](bf16* Kd, bf16* Vd, int kv0) {
    const bf16* kg = kgbase + (size_t)kv0 * NQKV;
    gload_lds16(kg, Kd + tid * 8);
    gload_lds16(kg + (size_t)32 * NQKV, Kd + 2048 + tid * 8);
    const bf16* vg = vgbase + kv0;
    gload_lds16(vg, Vd + tid * 8);
    gload_lds16(vg + 32 * NT, Vd + 2048 + tid * 8);
  };

  // Q fragments (post-RoPE): B-operand, col=q=ql, k=d=sub*8+j (+32c)
  bf16x8 qf[2][2];
#pragma unroll
  for (int set = 0; set < 2; ++set) {
    const bf16* qp = qkv + (size_t)(b * NT + q0 + wid * 32 + set * 16 + ql) * NQKV + h * 64 + sub * 8;
    qf[set][0] = *(const bf16x8*)qp;
    qf[set][1] = *(const bf16x8*)(qp + 32);
  }

  f32x4 o[2][4] = {};
  float m_s[2] = {-1e30f, -1e30f};
  float l_s[2] = {0.f, 0.f};
  const float C = 0.18033688011112042f;  // 0.125 * log2(e)

  const int ntiles = 2 * qtb + 2;
  STAGE(Kb0, Vb0, 0);
  __syncthreads();

  int cur = 0;
  for (int it = 0; it < ntiles; ++it) {
    const int kv0 = it * 64;
    bf16* Ksb = cur ? Kb1 : Kb0;
    bf16* Vsb = cur ? Vb1 : Vb0;
    if (it + 1 < ntiles) STAGE(cur ? Kb0 : Kb1, cur ? Vb0 : Vb1, kv0 + 64);

    if (kv0 <= q0 + wid * 32 + 47) {  // at least one set active for this wave
      // K fragments: LDS rows are pre-permuted -> linear row n*16+ql read,
      // XOR spans all 8 slots (2-way, free).
      bf16x8 kf[4][2];
#pragma unroll
      for (int n = 0; n < 4; ++n)
#pragma unroll
        for (int c = 0; c < 2; ++c)
          kf[n][c] = *(const bf16x8*)((const char*)Ksb + swz(n * 16 + ql, c * 64 + sub * 16));
      // V^T fragments: A-operand, row=d=dt*16+ql, k=kv=kc*32+sub*8+j
      bf16x8 vf[2][4];
#pragma unroll
      for (int kc = 0; kc < 2; ++kc)
#pragma unroll
        for (int dt = 0; dt < 4; ++dt)
          vf[kc][dt] = *(const bf16x8*)((const char*)Vsb + swz(dt * 16 + ql, kc * 64 + sub * 16));

#pragma unroll
      for (int set = 0; set < 2; ++set) {
        const int qlo = q0 + wid * 32 + set * 16;
        if (kv0 > qlo + 15) continue;  // fully masked for this set

        f32x4 s[4] = {};
        __builtin_amdgcn_s_setprio(1);
#pragma unroll
        for (int n = 0; n < 4; ++n) {
          s[n] = __builtin_amdgcn_mfma_f32_16x16x32_bf16(kf[n][0], qf[set][0], s[n], 0, 0, 0);
          s[n] = __builtin_amdgcn_mfma_f32_16x16x32_bf16(kf[n][1], qf[set][1], s[n], 0, 0, 0);
        }
        __builtin_amdgcn_s_setprio(0);

        // lane holds S^T[kv = kv0+32(n>>1)+4(n&1)+8sub+j][q = qlo+ql]
        float p[4][4];
        if (kv0 + 63 > qlo) {
          const int qrow = qlo + ql;
#pragma unroll
          for (int n = 0; n < 4; ++n) {
            const int kvb = kv0 + 32 * (n >> 1) + 4 * (n & 1) + 8 * sub;
#pragma unroll
            for (int j = 0; j < 4; ++j) {
              float v = s[n][j] * C;
              if (kvb + j > qrow) v = -1e30f;
              p[n][j] = v;
            }
          }
        } else {
#pragma unroll
          for (int n = 0; n < 4; ++n)
#pragma unroll
            for (int j = 0; j < 4; ++j)
              p[n][j] = s[n][j] * C;
        }

        // in-register online softmax, log2 domain (column q lives in lanes
        // ql+{0,16,32,48})
        float rmax = p[0][0];
#pragma unroll
        for (int n = 0; n < 4; ++n)
#pragma unroll
          for (int j = 0; j < 4; ++j) rmax = fmaxf(rmax, p[n][j]);
        rmax = fmaxf(rmax, __shfl_xor(rmax, 16));
        rmax = fmaxf(rmax, __shfl_xor(rmax, 32));

        // defer-max (T13): only rescale when the max grew by > 8 (log2)
        if (!__all(rmax <= m_s[set] + 8.0f)) {
          const float mnew = fmaxf(m_s[set], rmax);
          const float sc = exp2f(m_s[set] - mnew);
          m_s[set] = mnew;
          l_s[set] *= sc;
#pragma unroll
          for (int dt = 0; dt < 4; ++dt) o[set][dt] *= sc;
        }
        const float mcur = m_s[set];

        float rsum = 0.f;
        bf16x8 pb[2];  // [kc]: elements 0-3 from tile 2kc, 4-7 from tile 2kc+1
#pragma unroll
        for (int n = 0; n < 4; ++n)
#pragma unroll
          for (int j = 0; j < 4; ++j) {
            const float e = exp2f(p[n][j] - mcur);
            rsum += e;
            pb[n >> 1][(n & 1) * 4 + j] = (bf16)e;
          }
        rsum += __shfl_xor(rsum, 16);
        rsum += __shfl_xor(rsum, 32);
        l_s[set] += rsum;

        // O^T[d][q] += V^T[d][kv] * P^T[kv][q]  (full-rate x32, P in-register)
        __builtin_amdgcn_s_setprio(1);
#pragma unroll
        for (int kc = 0; kc < 2; ++kc)
#pragma unroll
          for (int dt = 0; dt < 4; ++dt)
            o[set][dt] = __builtin_amdgcn_mfma_f32_16x16x32_bf16(vf[kc][dt], pb[kc], o[set][dt], 0, 0, 0);
        __builtin_amdgcn_s_setprio(0);
      }
    }
    __syncthreads();  // drains vmcnt (next tile staged) + all waves done with cur
    cur ^= 1;
  }

  // epilogue: o[set][dt][j] = O[q=qlo+ql][d=dt*16+sub*4+j]
#pragma unroll
  for (int set = 0; set < 2; ++set) {
    const float inv = 1.0f / l_s[set];
    bf16* yp = y + (size_t)(b * NT + q0 + wid * 32 + set * 16 + ql) * NE + h * 64 + sub * 4;
#pragma unroll
    for (int dt = 0; dt < 4; ++dt) {
      bf16x4v w;
      w[0] = (bf16)(o[set][dt][0] * inv);
      w[1] = (bf16)(o[set][dt][1] * inv);
      w[2] = (bf16)(o[set][dt][2] * inv);
      w[3] = (bf16)(o[set][dt][3] * inv);
      *(bf16x4v*)(yp + dt * 16) = w;
    }
  }
}

// ---------------------------------------------------------------- launch

extern "C" void kernel_launch(void* const* d_in, const int* in_sizes, int n_in,
                              void* d_out, int out_size, void* d_ws, size_t ws_size,
                              hipStream_t stream) {
  const float* x = (const float*)d_in[0];
  const float* Wq = (const float*)d_in[1];
  const float* Wk = (const float*)d_in[2];
  const float* Wv = (const float*)d_in[3];
  const float* Wo = (const float*)d_in[4];
  float* out = (float*)d_out;

  char* ws = (char*)d_ws;
  size_t off = 0;
  auto alloc = [&](size_t bytes) -> void* {
    void* p = ws + off;
    off += (bytes + 255) & ~(size_t)255;
    return p;
  };
  bf16* xb = (bf16*)alloc((size_t)NBT * NE * 2);
  bf16* wqkv_t = (bf16*)alloc((size_t)NQKV * NE * 2);
  bf16* wo_t = (bf16*)alloc((size_t)NE * NE * 2);
  bf16* qkv = (bf16*)alloc((size_t)NBT * NQKV * 2);
  bf16* vtb = (bf16*)alloc((size_t)NB * NHKV * ND * NT * 2);
  bf16* yb = (bf16*)alloc((size_t)NBT * NE * 2);
  float* tab = (float*)alloc((size_t)NT * 64 * 4);

  cvt_bf16_kernel<<<2048, 256, 0, stream>>>(x, xb, NBT * NE / 4);
  dim3 tb(32, 8);
  transpose_cvt_kernel<<<dim3(64, 64), tb, 0, stream>>>(Wq, wqkv_t, 2048, 0);
  transpose_cvt_kernel<<<dim3(16, 64), tb, 0, stream>>>(Wk, wqkv_t, 512, 2048);
  transpose_cvt_kernel<<<dim3(16, 64), tb, 0, stream>>>(Wv, wqkv_t, 512, 2560);
  transpose_cvt_kernel<<<dim3(64, 64), tb, 0, stream>>>(Wo, wo_t, 2048, 0);
  rope_table_kernel<<<(NT * 32 + 255) / 256, 256, 0, stream>>>(tab);

  gemm8p_kernel<bf16, true><<<dim3((NQKV / 128) * (NBT / 256)), 512, 0, stream>>>(
      xb, wqkv_t, qkv, NBT, NQKV, NE, tab);
  build_vt_kernel<<<dim3(2, 64, 16), tb, 0, stream>>>(qkv, vtb);
  attn_kernel<<<dim3(NT / 128 * 64), 256, 0, stream>>>(qkv, vtb, yb);
  gemm8p_kernel<float, false><<<dim3((NE / 128) * (NBT / 256)), 512, 0, stream>>>(
      yb, wo_t, out, NBT, NE, NE, nullptr);
}

// Round 6
// 204.644 us; speedup vs baseline: 1.2577x; 1.2577x over previous
//
#include <hip/hip_runtime.h>
#include <hip/hip_bf16.h>
#include <cstdint>
#include <cstddef>

typedef __bf16 bf16;
typedef __attribute__((ext_vector_type(8))) __bf16 bf16x8;
typedef __attribute__((ext_vector_type(4))) __bf16 bf16x4v;
typedef __attribute__((ext_vector_type(4))) float f32x4;

#define NB 2
#define NT 2048
#define NE 2048
#define NH 32
#define NHKV 8
#define ND 64
#define NBT (NB * NT)
#define NQKV 3072

__device__ __forceinline__ void gload_lds16(const void* g, void* l) {
  __builtin_amdgcn_global_load_lds(
      (const __attribute__((address_space(1))) unsigned int*)g,
      (__attribute__((address_space(3))) unsigned int*)l, 16, 0, 0);
}

// XOR swizzle for 128-byte LDS rows: spreads the 16-way bank conflict.
__device__ __forceinline__ int swz(int row, int byteoff) {
  return (row * 128 + byteoff) ^ ((row & 7) << 4);
}

// ---------------------------------------------------------------- pack kernels

__global__ void cvt_bf16_kernel(const float* __restrict__ in, bf16* __restrict__ out, int n4) {
  int i = blockIdx.x * blockDim.x + threadIdx.x;
  const int stride = gridDim.x * blockDim.x;
  for (; i < n4; i += stride) {
    const float4 v = ((const float4*)in)[i];
    bf16x4v o;
    o[0] = (bf16)v.x; o[1] = (bf16)v.y; o[2] = (bf16)v.z; o[3] = (bf16)v.w;
    ((bf16x4v*)out)[i] = o;
  }
}

// out[rowoff + c][k] = (bf16) in[k][c];  in: [2048][ncols] fp32, out LD = 2048
__global__ void transpose_cvt_kernel(const float* __restrict__ in, bf16* __restrict__ out,
                                     int ncols, int rowoff) {
  __shared__ float tile[32][33];
  const int c0 = blockIdx.x * 32;
  const int k0 = blockIdx.y * 32;
  const int tx = threadIdx.x, ty = threadIdx.y;
#pragma unroll
  for (int j = 0; j < 4; ++j)
    tile[ty + j * 8][tx] = in[(size_t)(k0 + ty + j * 8) * ncols + c0 + tx];
  __syncthreads();
#pragma unroll
  for (int j = 0; j < 4; ++j)
    out[(size_t)(rowoff + c0 + ty + j * 8) * 2048 + k0 + tx] = (bf16)tile[tx][ty + j * 8];
}

__global__ void rope_table_kernel(float* __restrict__ tab) {
  int i = blockIdx.x * 256 + threadIdx.x;
  if (i >= NT * 32) return;
  const int t = i >> 5, d = i & 31;
  const float inv = expf(-(float)d * 0.28782313662425574f);  // ln(10000)/32
  const float ang = (float)t * inv;
  tab[t * 64 + d] = cosf(ang);
  tab[t * 64 + 32 + d] = sinf(ang);
}

// vt[b][hk][d][t] = qkv[b*T+t][2560 + hk*64 + d]
__global__ void build_vt_kernel(const bf16* __restrict__ qkv, bf16* __restrict__ vt) {
  __shared__ bf16 tile[32][33];
  const int bhk = blockIdx.z;
  const int b = bhk >> 3, hk = bhk & 7;
  const int d0 = blockIdx.x * 32, t0 = blockIdx.y * 32;
  const int tx = threadIdx.x, ty = threadIdx.y;
#pragma unroll
  for (int j = 0; j < 4; ++j)
    tile[ty + j * 8][tx] = qkv[(size_t)(b * NT + t0 + ty + j * 8) * NQKV + 2560 + hk * 64 + d0 + tx];
  __syncthreads();
#pragma unroll
  for (int j = 0; j < 4; ++j)
    vt[((size_t)(b * NHKV + hk) * 64 + d0 + ty + j * 8) * NT + t0 + tx] = tile[tx][ty + j * 8];
}

// ---------------------------------------------------------------- GEMM (ring-3, never-drain)
// C[M][N] = A[M][K] * Bt[N][K]^T ; 128x128 tile, BK=32, 4 waves (m97 shape).
// Ring-3 LDS (48 KB -> 3 blocks/CU TLP) + prefetch distance 2 K-tiles +
// counted vmcnt(4) (never drained in steady state) + ONE raw barrier per
// K-tile. This replaces the __syncthreads full-drain (the measured ~20%
// m97 stall) while keeping 3-block implicit wave overlap (m114).
// ROPE epilogue: rotate (d,d+32) pairs for q/k heads (cols<2560) and fold
// the attention scale 0.125*log2(e) into Q (cols<2048).

template <typename CT, bool ROPE>
__global__ __launch_bounds__(256, 3)
void gemm_r3_kernel(const bf16* __restrict__ A, const bf16* __restrict__ Bt,
                    CT* __restrict__ C, int M, int N, int K,
                    const float* __restrict__ tab) {
  __shared__ __align__(16) bf16 As[3][128 * 32];
  __shared__ __align__(16) bf16 Bs[3][128 * 32];
  const int tid = threadIdx.x;
  const int lane = tid & 63, wid = tid >> 6;
  const int wr = wid >> 1, wc = wid & 1;
  // XCD-bijective swizzle (nwg % 8 == 0 for all our grids)
  const int cpx = (int)gridDim.x >> 3;
  const int swzb = ((int)blockIdx.x & 7) * cpx + ((int)blockIdx.x >> 3);
  const int gx = N >> 7;
  const int bx = swzb % gx, by = swzb / gx;
  const int m0 = by * 128, n0 = bx * 128;
  const int srow = tid >> 2;          // 0..63 staging row
  const int skoff = (tid & 3) * 8;    // staging k offset
  const bf16* ga = A + (size_t)(m0 + srow) * K + skoff;
  const bf16* gb = Bt + (size_t)(n0 + srow) * K + skoff;
  const int fr = lane & 15;
  const int fk = (lane >> 4) * 8;
  const int NTK = K >> 5;
  f32x4 acc[4][4] = {};

#define STAGE_T(b, t)                                                   \
  do {                                                                  \
    const int kk = (t) * 32;                                            \
    gload_lds16(ga + kk, &As[b][tid * 8]);                              \
    gload_lds16(ga + kk + (size_t)64 * K, &As[b][2048 + tid * 8]);      \
    gload_lds16(gb + kk, &Bs[b][tid * 8]);                              \
    gload_lds16(gb + kk + (size_t)64 * K, &Bs[b][2048 + tid * 8]);      \
  } while (0)

  STAGE_T(0, 0);
  STAGE_T(1, 1);

  int bc = 0;
  for (int t = 0; t < NTK; ++t) {
    if (t + 1 < NTK) asm volatile("s_waitcnt vmcnt(4)" ::: "memory");
    else             asm volatile("s_waitcnt vmcnt(0)" ::: "memory");
    __builtin_amdgcn_s_barrier();

    bf16x8 af[4], bfr[4];
#pragma unroll
    for (int m = 0; m < 4; ++m)
      af[m] = *(const bf16x8*)&As[bc][(wr * 64 + m * 16 + fr) * 32 + fk];
#pragma unroll
    for (int n = 0; n < 4; ++n)
      bfr[n] = *(const bf16x8*)&Bs[bc][(wc * 64 + n * 16 + fr) * 32 + fk];

    if (t + 2 < NTK) {
      const int pb = (bc + 2 >= 3) ? bc - 1 : bc + 2;
      STAGE_T(pb, t + 2);
    }

    __builtin_amdgcn_s_setprio(1);
#pragma unroll
    for (int m = 0; m < 4; ++m)
#pragma unroll
      for (int n = 0; n < 4; ++n)
        acc[m][n] = __builtin_amdgcn_mfma_f32_16x16x32_bf16(af[m], bfr[n], acc[m][n], 0, 0, 0);
    __builtin_amdgcn_s_setprio(0);
    bc = (bc + 1 == 3) ? 0 : bc + 1;
  }
#undef STAGE_T

  const int colbase = n0 + wc * 64;
  const bool do_rope = ROPE && colbase < 2560;
  const bool do_scale = ROPE && colbase < 2048;
  const float SCALE = 0.18033688011112042f;  // 0.125 * log2(e)
  const int orow0 = m0 + wr * 64 + (lane >> 4) * 4;
  const int ocol0 = colbase + fr;
#pragma unroll
  for (int m = 0; m < 4; ++m) {
#pragma unroll
    for (int j = 0; j < 4; ++j) {
      const int row = orow0 + m * 16 + j;
      float v0 = acc[m][0][j], v1 = acc[m][1][j], v2 = acc[m][2][j], v3 = acc[m][3][j];
      if (do_rope) {
        const int tt = row & (NT - 1);
        const float c0 = tab[tt * 64 + fr],      s0 = tab[tt * 64 + 32 + fr];
        const float c1 = tab[tt * 64 + 16 + fr], s1 = tab[tt * 64 + 48 + fr];
        const float a0 = v0, a2 = v2;
        v0 = a0 * c0 - a2 * s0;
        v2 = a2 * c0 + a0 * s0;
        const float a1 = v1, a3 = v3;
        v1 = a1 * c1 - a3 * s1;
        v3 = a3 * c1 + a1 * s1;
        if (do_scale) { v0 *= SCALE; v1 *= SCALE; v2 *= SCALE; v3 *= SCALE; }
      }
      CT* cp = &C[(size_t)row * N + ocol0];
      cp[0] = (CT)v0; cp[16] = (CT)v1; cp[32] = (CT)v2; cp[48] = (CT)v3;
    }
  }
}

// ---------------------------------------------------------------- attention
// Swapped-operand flash attention. One block = 128 q rows of one (b,h).
// 4 waves x 32 q rows (2 sets of 16). KVBLK = 64, causal.
// Ring-3 K/V LDS + counted vmcnt(4) + ONE raw barrier per tile (no
// __syncthreads drain). Grid is 1-D global big-first. K stored row-permuted
// (source-permuted global_load_lds) so kf reads are conflict-free.
// Q is pre-scaled by 0.125*log2(e) in the GEMM1 epilogue -> p = s directly.
// Softmax in log2 domain with defer-max (T13); setprio around MFMA (T5).

__global__ __launch_bounds__(256, 3)
void attn_kernel(const bf16* __restrict__ qkv, const bf16* __restrict__ vt,
                 bf16* __restrict__ y) {
  const int bid = blockIdx.x;
  const int qtb = 15 - (bid >> 6);   // big blocks dispatched first
  const int bh = bid & 63;
  const int b = bh >> 5, h = bh & 31, hk = h >> 2;
  const int q0 = qtb * 128;

  __shared__ __align__(16) bf16 Kb[3][4096], Vb[3][4096];

  const int tid = threadIdx.x;
  const int lane = tid & 63, wid = tid >> 6;
  const int ql = lane & 15;
  const int sub = lane >> 4;

  // staging: dest linear row st_r / st_r+32, chunk tid&7; source column chunk
  // pre-swizzled by dest row (rule #21); K source ROW permuted so that LDS
  // row u holds kv 32(n>>1)+4(n&1)+8(t>>2)+(t&3), n=u>>4, t=u&15.
  const int st_r = tid >> 3;
  const int kperm = 4 * (st_r >> 4) + 8 * ((st_r >> 2) & 3) + (st_r & 3);
  const int csw = ((tid & 7) ^ (st_r & 7)) * 8;
  const bf16* kgbase = qkv + (size_t)(b * NT + kperm) * NQKV + 2048 + hk * 64 + csw;
  const bf16* vgbase = vt + ((size_t)(b * NHKV + hk) * 64 + st_r) * NT + csw;

  auto STAGE = [&](int buf, int kv0) {
    const bf16* kg = kgbase + (size_t)kv0 * NQKV;
    gload_lds16(kg, Kb[buf] + tid * 8);
    gload_lds16(kg + (size_t)32 * NQKV, Kb[buf] + 2048 + tid * 8);
    const bf16* vg = vgbase + kv0;
    gload_lds16(vg, Vb[buf] + tid * 8);
    gload_lds16(vg + 32 * NT, Vb[buf] + 2048 + tid * 8);
  };

  // Q fragments (post-RoPE, pre-scaled): B-operand, col=q=ql, k=d=sub*8+j
  bf16x8 qf[2][2];
#pragma unroll
  for (int set = 0; set < 2; ++set) {
    const bf16* qp = qkv + (size_t)(b * NT + q0 + wid * 32 + set * 16 + ql) * NQKV + h * 64 + sub * 8;
    qf[set][0] = *(const bf16x8*)qp;
    qf[set][1] = *(const bf16x8*)(qp + 32);
  }

  f32x4 o[2][4] = {};
  float m_s[2] = {-1e30f, -1e30f};
  float l_s[2] = {0.f, 0.f};

  const int ntiles = 2 * qtb + 2;
  STAGE(0, 0);
  STAGE(1, 64);

  int bc = 0;
  for (int it = 0; it < ntiles; ++it) {
    const int kv0 = it * 64;
    if (it + 1 < ntiles) asm volatile("s_waitcnt vmcnt(4)" ::: "memory");
    else                 asm volatile("s_waitcnt vmcnt(0)" ::: "memory");
    __builtin_amdgcn_s_barrier();

    if (it + 2 < ntiles) {
      const int pb = (bc + 2 >= 3) ? bc - 1 : bc + 2;
      STAGE(pb, kv0 + 128);
    }

    if (kv0 <= q0 + wid * 32 + 47) {  // at least one set active for this wave
      // K fragments: LDS rows pre-permuted -> linear row n*16+ql read.
      bf16x8 kf[4][2];
#pragma unroll
      for (int n = 0; n < 4; ++n)
#pragma unroll
        for (int c = 0; c < 2; ++c)
          kf[n][c] = *(const bf16x8*)((const char*)Kb[bc] + swz(n * 16 + ql, c * 64 + sub * 16));
      // V^T fragments: A-operand, row=d=dt*16+ql, k=kv=kc*32+sub*8+j
      bf16x8 vf[2][4];
#pragma unroll
      for (int kc = 0; kc < 2; ++kc)
#pragma unroll
        for (int dt = 0; dt < 4; ++dt)
          vf[kc][dt] = *(const bf16x8*)((const char*)Vb[bc] + swz(dt * 16 + ql, kc * 64 + sub * 16));

#pragma unroll
      for (int set = 0; set < 2; ++set) {
        const int qlo = q0 + wid * 32 + set * 16;
        if (kv0 > qlo + 15) continue;  // fully masked for this set

        f32x4 s[4] = {};
        __builtin_amdgcn_s_setprio(1);
#pragma unroll
        for (int n = 0; n < 4; ++n) {
          s[n] = __builtin_amdgcn_mfma_f32_16x16x32_bf16(kf[n][0], qf[set][0], s[n], 0, 0, 0);
          s[n] = __builtin_amdgcn_mfma_f32_16x16x32_bf16(kf[n][1], qf[set][1], s[n], 0, 0, 0);
        }
        __builtin_amdgcn_s_setprio(0);

        // lane holds S^T[kv = kv0+32(n>>1)+4(n&1)+8sub+j][q = qlo+ql],
        // already in log2-softmax units (Q pre-scaled).
        float p[4][4];
        if (kv0 + 63 > qlo) {
          const int qrow = qlo + ql;
#pragma unroll
          for (int n = 0; n < 4; ++n) {
            const int kvb = kv0 + 32 * (n >> 1) + 4 * (n & 1) + 8 * sub;
#pragma unroll
            for (int j = 0; j < 4; ++j)
              p[n][j] = (kvb + j > qrow) ? -1e30f : s[n][j];
          }
        } else {
#pragma unroll
          for (int n = 0; n < 4; ++n)
#pragma unroll
            for (int j = 0; j < 4; ++j)
              p[n][j] = s[n][j];
        }

        // in-register online softmax, log2 domain (column q lives in lanes
        // ql+{0,16,32,48})
        float rmax = p[0][0];
#pragma unroll
        for (int n = 0; n < 4; ++n)
#pragma unroll
          for (int j = 0; j < 4; ++j) rmax = fmaxf(rmax, p[n][j]);
        rmax = fmaxf(rmax, __shfl_xor(rmax, 16));
        rmax = fmaxf(rmax, __shfl_xor(rmax, 32));

        // defer-max (T13): only rescale when the max grew by > 8 (log2)
        if (!__all(rmax <= m_s[set] + 8.0f)) {
          const float mnew = fmaxf(m_s[set], rmax);
          const float sc = exp2f(m_s[set] - mnew);
          m_s[set] = mnew;
          l_s[set] *= sc;
#pragma unroll
          for (int dt = 0; dt < 4; ++dt) o[set][dt] *= sc;
        }
        const float mcur = m_s[set];

        float rsum = 0.f;
        bf16x8 pb2[2];  // [kc]: elements 0-3 from tile 2kc, 4-7 from tile 2kc+1
#pragma unroll
        for (int n = 0; n < 4; ++n)
#pragma unroll
          for (int j = 0; j < 4; ++j) {
            const float e = exp2f(p[n][j] - mcur);
            rsum += e;
            pb2[n >> 1][(n & 1) * 4 + j] = (bf16)e;
          }
        rsum += __shfl_xor(rsum, 16);
        rsum += __shfl_xor(rsum, 32);
        l_s[set] += rsum;

        // O^T[d][q] += V^T[d][kv] * P^T[kv][q]  (full-rate x32, P in-register)
        __builtin_amdgcn_s_setprio(1);
#pragma unroll
        for (int kc = 0; kc < 2; ++kc)
#pragma unroll
          for (int dt = 0; dt < 4; ++dt)
            o[set][dt] = __builtin_amdgcn_mfma_f32_16x16x32_bf16(vf[kc][dt], pb2[kc], o[set][dt], 0, 0, 0);
        __builtin_amdgcn_s_setprio(0);
      }
    }
    bc = (bc + 1 == 3) ? 0 : bc + 1;
  }

  // epilogue: o[set][dt][j] = O[q=qlo+ql][d=dt*16+sub*4+j]
#pragma unroll
  for (int set = 0; set < 2; ++set) {
    const float inv = 1.0f / l_s[set];
    bf16* yp = y + (size_t)(b * NT + q0 + wid * 32 + set * 16 + ql) * NE + h * 64 + sub * 4;
#pragma unroll
    for (int dt = 0; dt < 4; ++dt) {
      bf16x4v w;
      w[0] = (bf16)(o[set][dt][0] * inv);
      w[1] = (bf16)(o[set][dt][1] * inv);
      w[2] = (bf16)(o[set][dt][2] * inv);
      w[3] = (bf16)(o[set][dt][3] * inv);
      *(bf16x4v*)(yp + dt * 16) = w;
    }
  }
}

// ---------------------------------------------------------------- launch

extern "C" void kernel_launch(void* const* d_in, const int* in_sizes, int n_in,
                              void* d_out, int out_size, void* d_ws, size_t ws_size,
                              hipStream_t stream) {
  const float* x = (const float*)d_in[0];
  const float* Wq = (const float*)d_in[1];
  const float* Wk = (const float*)d_in[2];
  const float* Wv = (const float*)d_in[3];
  const float* Wo = (const float*)d_in[4];
  float* out = (float*)d_out;

  char* ws = (char*)d_ws;
  size_t off = 0;
  auto alloc = [&](size_t bytes) -> void* {
    void* p = ws + off;
    off += (bytes + 255) & ~(size_t)255;
    return p;
  };
  bf16* xb = (bf16*)alloc((size_t)NBT * NE * 2);
  bf16* wqkv_t = (bf16*)alloc((size_t)NQKV * NE * 2);
  bf16* wo_t = (bf16*)alloc((size_t)NE * NE * 2);
  bf16* qkv = (bf16*)alloc((size_t)NBT * NQKV * 2);
  bf16* vtb = (bf16*)alloc((size_t)NB * NHKV * ND * NT * 2);
  bf16* yb = (bf16*)alloc((size_t)NBT * NE * 2);
  float* tab = (float*)alloc((size_t)NT * 64 * 4);

  cvt_bf16_kernel<<<2048, 256, 0, stream>>>(x, xb, NBT * NE / 4);
  dim3 tb(32, 8);
  transpose_cvt_kernel<<<dim3(64, 64), tb, 0, stream>>>(Wq, wqkv_t, 2048, 0);
  transpose_cvt_kernel<<<dim3(16, 64), tb, 0, stream>>>(Wk, wqkv_t, 512, 2048);
  transpose_cvt_kernel<<<dim3(16, 64), tb, 0, stream>>>(Wv, wqkv_t, 512, 2560);
  transpose_cvt_kernel<<<dim3(64, 64), tb, 0, stream>>>(Wo, wo_t, 2048, 0);
  rope_table_kernel<<<(NT * 32 + 255) / 256, 256, 0, stream>>>(tab);

  gemm_r3_kernel<bf16, true><<<dim3((NQKV / 128) * (NBT / 128)), 256, 0, stream>>>(
      xb, wqkv_t, qkv, NBT, NQKV, NE, tab);
  build_vt_kernel<<<dim3(2, 64, 16), tb, 0, stream>>>(qkv, vtb);
  attn_kernel<<<dim3(NT / 128 * 64), 256, 0, stream>>>(qkv, vtb, yb);
  gemm_r3_kernel<float, false><<<dim3((NE / 128) * (NBT / 128)), 256, 0, stream>>>(
      yb, wo_t, out, NBT, NE, NE, nullptr);
}

// Round 7
// 199.525 us; speedup vs baseline: 1.2899x; 1.0257x over previous
//
#include <hip/hip_runtime.h>
#include <hip/hip_bf16.h>
#include <cstdint>
#include <cstddef>

typedef __bf16 bf16;
typedef __attribute__((ext_vector_type(8))) __bf16 bf16x8;
typedef __attribute__((ext_vector_type(4))) __bf16 bf16x4v;
typedef __attribute__((ext_vector_type(4))) float f32x4;

#define NB 2
#define NT 2048
#define NE 2048
#define NH 32
#define NHKV 8
#define ND 64
#define NBT (NB * NT)
#define NQKV 3072

__device__ __forceinline__ void gload_lds16(const void* g, void* l) {
  __builtin_amdgcn_global_load_lds(
      (const __attribute__((address_space(1))) unsigned int*)g,
      (__attribute__((address_space(3))) unsigned int*)l, 16, 0, 0);
}

// XOR swizzle for 128-byte LDS rows: spreads the 16-way bank conflict.
__device__ __forceinline__ int swz(int row, int byteoff) {
  return (row * 128 + byteoff) ^ ((row & 7) << 4);
}

// ---------------------------------------------------------------- pack kernels

__global__ void cvt_bf16_kernel(const float* __restrict__ in, bf16* __restrict__ out, int n4) {
  int i = blockIdx.x * blockDim.x + threadIdx.x;
  const int stride = gridDim.x * blockDim.x;
  for (; i < n4; i += stride) {
    const float4 v = ((const float4*)in)[i];
    bf16x4v o;
    o[0] = (bf16)v.x; o[1] = (bf16)v.y; o[2] = (bf16)v.z; o[3] = (bf16)v.w;
    ((bf16x4v*)out)[i] = o;
  }
}

// out[rowoff + c][k] = (bf16) in[k][c];  in: [2048][ncols] fp32, out LD = 2048
__global__ void transpose_cvt_kernel(const float* __restrict__ in, bf16* __restrict__ out,
                                     int ncols, int rowoff) {
  __shared__ float tile[32][33];
  const int c0 = blockIdx.x * 32;
  const int k0 = blockIdx.y * 32;
  const int tx = threadIdx.x, ty = threadIdx.y;
#pragma unroll
  for (int j = 0; j < 4; ++j)
    tile[ty + j * 8][tx] = in[(size_t)(k0 + ty + j * 8) * ncols + c0 + tx];
  __syncthreads();
#pragma unroll
  for (int j = 0; j < 4; ++j)
    out[(size_t)(rowoff + c0 + ty + j * 8) * 2048 + k0 + tx] = (bf16)tile[tx][ty + j * 8];
}

__global__ void rope_table_kernel(float* __restrict__ tab) {
  int i = blockIdx.x * 256 + threadIdx.x;
  if (i >= NT * 32) return;
  const int t = i >> 5, d = i & 31;
  const float inv = expf(-(float)d * 0.28782313662425574f);  // ln(10000)/32
  const float ang = (float)t * inv;
  tab[t * 64 + d] = cosf(ang);
  tab[t * 64 + 32 + d] = sinf(ang);
}

// ---------------------------------------------------------------- GEMM (ring-3, never-drain, T2-swizzled)
// C[M][N] = A[M][K] * Bt[N][K]^T ; 128x128 tile, BK=32, 4 waves.
// Ring-3 LDS (48 KB -> 3 blocks/CU TLP) + prefetch distance 2 K-tiles +
// counted vmcnt(4) + ONE raw barrier per K-tile.
// T2: LDS rows are 64 B; un-swizzled fragment reads are 8-way bank
// conflicted (~540 TF cap). Fix (rule #21, both sides): staging SOURCE
// chunk = slot ^ ((row>>1)&3)  (row = tid>>2 -> (tid>>3)&3), fragment read
// slot = fq ^ ((fr>>1)&3) -> 8 distinct bank groups, 2-way (free).
// ROPE epilogue: rotate (d,d+32) pairs for q/k heads (cols<2560), fold
// 0.125*log2(e) into Q (cols<2048), and write V panel (cols>=2560)
// TRANSPOSED into vt[b][hk][d][t] (replaces the build_vt kernel).

template <typename CT, bool ROPE>
__global__ __launch_bounds__(256, 3)
void gemm_r3_kernel(const bf16* __restrict__ A, const bf16* __restrict__ Bt,
                    CT* __restrict__ C, int M, int N, int K,
                    const float* __restrict__ tab, bf16* __restrict__ vt) {
  __shared__ __align__(16) bf16 As[3][128 * 32];
  __shared__ __align__(16) bf16 Bs[3][128 * 32];
  const int tid = threadIdx.x;
  const int lane = tid & 63, wid = tid >> 6;
  const int wr = wid >> 1, wc = wid & 1;
  // XCD-bijective swizzle (nwg % 8 == 0 for all our grids)
  const int cpx = (int)gridDim.x >> 3;
  const int swzb = ((int)blockIdx.x & 7) * cpx + ((int)blockIdx.x >> 3);
  const int gx = N >> 7;
  const int bx = swzb % gx, by = swzb / gx;
  const int m0 = by * 128, n0 = bx * 128;
  const int srow = tid >> 2;                              // 0..63 staging row
  const int skoff = 8 * ((tid & 3) ^ ((tid >> 3) & 3));   // T2 source swizzle
  const bf16* ga = A + (size_t)(m0 + srow) * K + skoff;
  const bf16* gb = Bt + (size_t)(n0 + srow) * K + skoff;
  const int fr = lane & 15;
  const int fq = lane >> 4;
  const int fks = 8 * (fq ^ ((fr >> 1) & 3));             // T2 read swizzle
  const int NTK = K >> 5;
  f32x4 acc[4][4] = {};

#define STAGE_T(b, t)                                                   \
  do {                                                                  \
    const int kk = (t) * 32;                                            \
    gload_lds16(ga + kk, &As[b][tid * 8]);                              \
    gload_lds16(ga + kk + (size_t)64 * K, &As[b][2048 + tid * 8]);      \
    gload_lds16(gb + kk, &Bs[b][tid * 8]);                              \
    gload_lds16(gb + kk + (size_t)64 * K, &Bs[b][2048 + tid * 8]);      \
  } while (0)

  STAGE_T(0, 0);
  STAGE_T(1, 1);

  int bc = 0;
  for (int t = 0; t < NTK; ++t) {
    if (t + 1 < NTK) asm volatile("s_waitcnt vmcnt(4)" ::: "memory");
    else             asm volatile("s_waitcnt vmcnt(0)" ::: "memory");
    __builtin_amdgcn_s_barrier();

    bf16x8 af[4], bfr[4];
#pragma unroll
    for (int m = 0; m < 4; ++m)
      af[m] = *(const bf16x8*)&As[bc][(wr * 64 + m * 16 + fr) * 32 + fks];
#pragma unroll
    for (int n = 0; n < 4; ++n)
      bfr[n] = *(const bf16x8*)&Bs[bc][(wc * 64 + n * 16 + fr) * 32 + fks];

    if (t + 2 < NTK) {
      const int pb = (bc + 2 >= 3) ? bc - 1 : bc + 2;
      STAGE_T(pb, t + 2);
    }

    __builtin_amdgcn_s_setprio(1);
#pragma unroll
    for (int m = 0; m < 4; ++m)
#pragma unroll
      for (int n = 0; n < 4; ++n)
        acc[m][n] = __builtin_amdgcn_mfma_f32_16x16x32_bf16(af[m], bfr[n], acc[m][n], 0, 0, 0);
    __builtin_amdgcn_s_setprio(0);
    bc = (bc + 1 == 3) ? 0 : bc + 1;
  }
#undef STAGE_T

  const int colbase = n0 + wc * 64;

  if (ROPE && colbase >= 2560) {
    // V panel: write transposed into vt[b][hk][d][t] (no qkv write needed).
    const int hk = (colbase - 2560) >> 6;
    const int bb = m0 >> 11;
    const int t0 = (m0 & (NT - 1)) + wr * 64 + fq * 4;
    bf16* vtp = vt + (size_t)(bb * NHKV + hk) * 64 * NT;
#pragma unroll
    for (int m = 0; m < 4; ++m) {
#pragma unroll
      for (int n = 0; n < 4; ++n) {
        const int d = n * 16 + fr;
        bf16x4v w;
        w[0] = (bf16)acc[m][n][0];
        w[1] = (bf16)acc[m][n][1];
        w[2] = (bf16)acc[m][n][2];
        w[3] = (bf16)acc[m][n][3];
        *(bf16x4v*)&vtp[(size_t)d * NT + t0 + m * 16] = w;
      }
    }
    return;
  }

  const bool do_rope = ROPE && colbase < 2560;
  const bool do_scale = ROPE && colbase < 2048;
  const float SCALE = 0.18033688011112042f;  // 0.125 * log2(e)
  const int orow0 = m0 + wr * 64 + fq * 4;
  const int ocol0 = colbase + fr;
#pragma unroll
  for (int m = 0; m < 4; ++m) {
#pragma unroll
    for (int j = 0; j < 4; ++j) {
      const int row = orow0 + m * 16 + j;
      float v0 = acc[m][0][j], v1 = acc[m][1][j], v2 = acc[m][2][j], v3 = acc[m][3][j];
      if (do_rope) {
        const int tt = row & (NT - 1);
        const float c0 = tab[tt * 64 + fr],      s0 = tab[tt * 64 + 32 + fr];
        const float c1 = tab[tt * 64 + 16 + fr], s1 = tab[tt * 64 + 48 + fr];
        const float a0 = v0, a2 = v2;
        v0 = a0 * c0 - a2 * s0;
        v2 = a2 * c0 + a0 * s0;
        const float a1 = v1, a3 = v3;
        v1 = a1 * c1 - a3 * s1;
        v3 = a3 * c1 + a1 * s1;
        if (do_scale) { v0 *= SCALE; v1 *= SCALE; v2 *= SCALE; v3 *= SCALE; }
      }
      CT* cp = &C[(size_t)row * N + ocol0];
      cp[0] = (CT)v0; cp[16] = (CT)v1; cp[32] = (CT)v2; cp[48] = (CT)v3;
    }
  }
}

// ---------------------------------------------------------------- attention
// Swapped-operand flash attention. One block = 128 q rows of one (b,h).
// 4 waves x 32 q rows (2 sets of 16). KVBLK = 64, causal.
// Ring-3 K/V LDS + counted vmcnt(4) + ONE raw barrier per tile. Grid is
// 1-D global big-first. K stored row-permuted (source-permuted
// global_load_lds) so kf reads are conflict-free. Q pre-scaled by
// 0.125*log2(e) in GEMM1. Softmax log2-domain with defer-max (T13);
// l = P*1 accumulated by MFMA (idle matrix pipe) instead of VALU adds.

__global__ __launch_bounds__(256, 3)
void attn_kernel(const bf16* __restrict__ qkv, const bf16* __restrict__ vt,
                 bf16* __restrict__ y) {
  const int bid = blockIdx.x;
  const int qtb = 15 - (bid >> 6);   // big blocks dispatched first
  const int bh = bid & 63;
  const int b = bh >> 5, h = bh & 31, hk = h >> 2;
  const int q0 = qtb * 128;

  __shared__ __align__(16) bf16 Kb[3][4096], Vb[3][4096];

  const int tid = threadIdx.x;
  const int lane = tid & 63, wid = tid >> 6;
  const int ql = lane & 15;
  const int sub = lane >> 4;

  const int st_r = tid >> 3;
  const int kperm = 4 * (st_r >> 4) + 8 * ((st_r >> 2) & 3) + (st_r & 3);
  const int csw = ((tid & 7) ^ (st_r & 7)) * 8;
  const bf16* kgbase = qkv + (size_t)(b * NT + kperm) * NQKV + 2048 + hk * 64 + csw;
  const bf16* vgbase = vt + ((size_t)(b * NHKV + hk) * 64 + st_r) * NT + csw;

  auto STAGE = [&](int buf, int kv0) {
    const bf16* kg = kgbase + (size_t)kv0 * NQKV;
    gload_lds16(kg, Kb[buf] + tid * 8);
    gload_lds16(kg + (size_t)32 * NQKV, Kb[buf] + 2048 + tid * 8);
    const bf16* vg = vgbase + kv0;
    gload_lds16(vg, Vb[buf] + tid * 8);
    gload_lds16(vg + 32 * NT, Vb[buf] + 2048 + tid * 8);
  };

  // Q fragments (post-RoPE, pre-scaled): B-operand, col=q=ql, k=d=sub*8+j
  bf16x8 qf[2][2];
#pragma unroll
  for (int set = 0; set < 2; ++set) {
    const bf16* qp = qkv + (size_t)(b * NT + q0 + wid * 32 + set * 16 + ql) * NQKV + h * 64 + sub * 8;
    qf[set][0] = *(const bf16x8*)qp;
    qf[set][1] = *(const bf16x8*)(qp + 32);
  }

  bf16x8 ones8;
#pragma unroll
  for (int i = 0; i < 8; ++i) ones8[i] = (bf16)1.0f;

  f32x4 o[2][4] = {};
  f32x4 ol[2] = {};               // l accumulator via MFMA (all 4 elems equal)
  float m_s[2] = {-1e30f, -1e30f};

  const int ntiles = 2 * qtb + 2;
  STAGE(0, 0);
  STAGE(1, 64);

  int bc = 0;
  for (int it = 0; it < ntiles; ++it) {
    const int kv0 = it * 64;
    if (it + 1 < ntiles) asm volatile("s_waitcnt vmcnt(4)" ::: "memory");
    else                 asm volatile("s_waitcnt vmcnt(0)" ::: "memory");
    __builtin_amdgcn_s_barrier();

    if (it + 2 < ntiles) {
      const int pb = (bc + 2 >= 3) ? bc - 1 : bc + 2;
      STAGE(pb, kv0 + 128);
    }

    if (kv0 <= q0 + wid * 32 + 47) {  // at least one set active for this wave
      bf16x8 kf[4][2];
#pragma unroll
      for (int n = 0; n < 4; ++n)
#pragma unroll
        for (int c = 0; c < 2; ++c)
          kf[n][c] = *(const bf16x8*)((const char*)Kb[bc] + swz(n * 16 + ql, c * 64 + sub * 16));
      bf16x8 vf[2][4];
#pragma unroll
      for (int kc = 0; kc < 2; ++kc)
#pragma unroll
        for (int dt = 0; dt < 4; ++dt)
          vf[kc][dt] = *(const bf16x8*)((const char*)Vb[bc] + swz(dt * 16 + ql, kc * 64 + sub * 16));

#pragma unroll
      for (int set = 0; set < 2; ++set) {
        const int qlo = q0 + wid * 32 + set * 16;
        if (kv0 > qlo + 15) continue;  // fully masked for this set

        f32x4 s[4] = {};
        __builtin_amdgcn_s_setprio(1);
#pragma unroll
        for (int n = 0; n < 4; ++n) {
          s[n] = __builtin_amdgcn_mfma_f32_16x16x32_bf16(kf[n][0], qf[set][0], s[n], 0, 0, 0);
          s[n] = __builtin_amdgcn_mfma_f32_16x16x32_bf16(kf[n][1], qf[set][1], s[n], 0, 0, 0);
        }
        __builtin_amdgcn_s_setprio(0);

        // lane holds S^T[kv = kv0+32(n>>1)+4(n&1)+8sub+j][q = qlo+ql],
        // already in log2-softmax units (Q pre-scaled).
        float p[4][4];
        if (kv0 + 63 > qlo) {
          const int qrow = qlo + ql;
#pragma unroll
          for (int n = 0; n < 4; ++n) {
            const int kvb = kv0 + 32 * (n >> 1) + 4 * (n & 1) + 8 * sub;
#pragma unroll
            for (int j = 0; j < 4; ++j)
              p[n][j] = (kvb + j > qrow) ? -1e30f : s[n][j];
          }
        } else {
#pragma unroll
          for (int n = 0; n < 4; ++n)
#pragma unroll
            for (int j = 0; j < 4; ++j)
              p[n][j] = s[n][j];
        }

        // in-register online softmax, log2 domain (column q lives in lanes
        // ql+{0,16,32,48})
        float rmax = p[0][0];
#pragma unroll
        for (int n = 0; n < 4; ++n)
#pragma unroll
          for (int j = 0; j < 4; ++j) rmax = fmaxf(rmax, p[n][j]);
        rmax = fmaxf(rmax, __shfl_xor(rmax, 16));
        rmax = fmaxf(rmax, __shfl_xor(rmax, 32));

        // defer-max (T13): only rescale when the max grew by > 8 (log2)
        if (!__all(rmax <= m_s[set] + 8.0f)) {
          const float mnew = fmaxf(m_s[set], rmax);
          const float sc = exp2f(m_s[set] - mnew);
          m_s[set] = mnew;
          ol[set] *= sc;
#pragma unroll
          for (int dt = 0; dt < 4; ++dt) o[set][dt] *= sc;
        }
        const float mcur = m_s[set];

        bf16x8 pb2[2];  // [kc]: elements 0-3 from tile 2kc, 4-7 from tile 2kc+1
#pragma unroll
        for (int n = 0; n < 4; ++n)
#pragma unroll
          for (int j = 0; j < 4; ++j)
            pb2[n >> 1][(n & 1) * 4 + j] = (bf16)exp2f(p[n][j] - mcur);

        // O^T[d][q] += V^T[d][kv] * P^T[kv][q]; l += 1^T * P (matrix pipe)
        __builtin_amdgcn_s_setprio(1);
#pragma unroll
        for (int kc = 0; kc < 2; ++kc) {
          ol[set] = __builtin_amdgcn_mfma_f32_16x16x32_bf16(ones8, pb2[kc], ol[set], 0, 0, 0);
#pragma unroll
          for (int dt = 0; dt < 4; ++dt)
            o[set][dt] = __builtin_amdgcn_mfma_f32_16x16x32_bf16(vf[kc][dt], pb2[kc], o[set][dt], 0, 0, 0);
        }
        __builtin_amdgcn_s_setprio(0);
      }
    }
    bc = (bc + 1 == 3) ? 0 : bc + 1;
  }

  // epilogue: o[set][dt][j] = O[q=qlo+ql][d=dt*16+sub*4+j]
#pragma unroll
  for (int set = 0; set < 2; ++set) {
    const float inv = 1.0f / ol[set][0];
    bf16* yp = y + (size_t)(b * NT + q0 + wid * 32 + set * 16 + ql) * NE + h * 64 + sub * 4;
#pragma unroll
    for (int dt = 0; dt < 4; ++dt) {
      bf16x4v w;
      w[0] = (bf16)(o[set][dt][0] * inv);
      w[1] = (bf16)(o[set][dt][1] * inv);
      w[2] = (bf16)(o[set][dt][2] * inv);
      w[3] = (bf16)(o[set][dt][3] * inv);
      *(bf16x4v*)(yp + dt * 16) = w;
    }
  }
}

// ---------------------------------------------------------------- launch

extern "C" void kernel_launch(void* const* d_in, const int* in_sizes, int n_in,
                              void* d_out, int out_size, void* d_ws, size_t ws_size,
                              hipStream_t stream) {
  const float* x = (const float*)d_in[0];
  const float* Wq = (const float*)d_in[1];
  const float* Wk = (const float*)d_in[2];
  const float* Wv = (const float*)d_in[3];
  const float* Wo = (const float*)d_in[4];
  float* out = (float*)d_out;

  char* ws = (char*)d_ws;
  size_t off = 0;
  auto alloc = [&](size_t bytes) -> void* {
    void* p = ws + off;
    off += (bytes + 255) & ~(size_t)255;
    return p;
  };
  bf16* xb = (bf16*)alloc((size_t)NBT * NE * 2);
  bf16* wqkv_t = (bf16*)alloc((size_t)NQKV * NE * 2);
  bf16* wo_t = (bf16*)alloc((size_t)NE * NE * 2);
  bf16* qkv = (bf16*)alloc((size_t)NBT * NQKV * 2);
  bf16* vtb = (bf16*)alloc((size_t)NB * NHKV * ND * NT * 2);
  bf16* yb = (bf16*)alloc((size_t)NBT * NE * 2);
  float* tab = (float*)alloc((size_t)NT * 64 * 4);

  cvt_bf16_kernel<<<2048, 256, 0, stream>>>(x, xb, NBT * NE / 4);
  dim3 tb(32, 8);
  transpose_cvt_kernel<<<dim3(64, 64), tb, 0, stream>>>(Wq, wqkv_t, 2048, 0);
  transpose_cvt_kernel<<<dim3(16, 64), tb, 0, stream>>>(Wk, wqkv_t, 512, 2048);
  transpose_cvt_kernel<<<dim3(16, 64), tb, 0, stream>>>(Wv, wqkv_t, 512, 2560);
  transpose_cvt_kernel<<<dim3(64, 64), tb, 0, stream>>>(Wo, wo_t, 2048, 0);
  rope_table_kernel<<<(NT * 32 + 255) / 256, 256, 0, stream>>>(tab);

  gemm_r3_kernel<bf16, true><<<dim3((NQKV / 128) * (NBT / 128)), 256, 0, stream>>>(
      xb, wqkv_t, qkv, NBT, NQKV, NE, tab, vtb);
  attn_kernel<<<dim3(NT / 128 * 64), 256, 0, stream>>>(qkv, vtb, yb);
  gemm_r3_kernel<float, false><<<dim3((NE / 128) * (NBT / 128)), 256, 0, stream>>>(
      yb, wo_t, out, NBT, NE, NE, nullptr, nullptr);
}